// Round 3
// baseline (176.264 us; speedup 1.0000x reference)
//
#include <hip/hip_runtime.h>
#include <stdint.h>

typedef __attribute__((ext_vector_type(8))) __bf16 bf16x8;
typedef __attribute__((ext_vector_type(4))) float f32x4;

#define N_PTS 1600
#define HD    64

// ---- workspace layout (bytes). Canonical inputs + WT are dead after k_proj;
// ---- Oacc4 (written only in k_attn, after proj) overlaps them. Total ~9.4 MB.
#define OFF_XC    0u
#define OFF_WQC   819200u
#define OFF_BQC   950272u
#define OFF_WKC   950784u
#define OFF_BKC   1081856u
#define OFF_WVC   1082368u
#define OFF_BVC   1213440u
#define OFF_WT    1213952u    //  393216 -> ends 1607168
#define OFF_OACC4 0u          // 6553600 : [4 kg][1600][256] f32 (overlaps the above)
#define OFF_QH    6553600u    //  819200 : [4][1600][64] bf16, pre-scaled 1/16
#define OFF_KH    7372800u    //  819200
#define OFF_VH    8192000u    //  819200
#define OFF_VST   9011200u    //  819200 : [4][64][1600] smoothed V, transposed
#define OFF_FLAG  9830400u    //       4 : 1 => inputs are f32, 0 => bf16

__device__ __forceinline__ float bf2f(ushort h) {
  union { uint32_t u; float f; } v; v.u = ((uint32_t)h) << 16; return v.f;
}
__device__ __forceinline__ ushort f2bf(float f) {
  union { float f; uint32_t u; } v; v.f = f;
  uint32_t u = v.u;
  return (ushort)((u + 0x7FFFu + ((u >> 16) & 1u)) >> 16);
}

// ---- dtype detector: even-indexed ushorts of an f32 buffer are mantissa garbage ----
__global__ void k_detect(const ushort* __restrict__ x, int* __restrict__ flag) {
  __shared__ int bad;
  if (threadIdx.x == 0) bad = 0;
  __syncthreads();
  int t = threadIdx.x;
  int local = 0;
#pragma unroll
  for (int i = 0; i < 16; ++i) {
    float v = bf2f(x[(t * 16 + i) * 2]);   // 4096 even indices, first 16 KB: safe either dtype
    if (!(fabsf(v) < 1e4f)) local = 1;     // catches huge values and NaN
  }
  if (local) atomicOr(&bad, 1);
  __syncthreads();
  if (t == 0) *flag = bad;
}

// ---- canonicalize all 7 inputs to bf16 in ws, per detected dtype ----
__global__ void k_convert(const void* __restrict__ s0, const void* __restrict__ s1,
                          const void* __restrict__ s2, const void* __restrict__ s3,
                          const void* __restrict__ s4, const void* __restrict__ s5,
                          const void* __restrict__ s6, char* __restrict__ ws,
                          const int* __restrict__ flag) {
  const int sizes[7] = {409600, 65536, 256, 65536, 256, 65536, 256};
  const unsigned offs[7] = {OFF_XC, OFF_WQC, OFF_BQC, OFF_WKC, OFF_BKC, OFF_WVC, OFF_BVC};
  const void* srcs[7] = {s0, s1, s2, s3, s4, s5, s6};
  int which = blockIdx.y;
  int i = blockIdx.x * 256 + threadIdx.x;
  if (i >= sizes[which]) return;
  const void* src = srcs[which];
  ushort* dst = (ushort*)(ws + offs[which]);
  if (*flag) dst[i] = f2bf(((const float*)src)[i]);
  else       dst[i] = ((const ushort*)src)[i];
}

// ---------------- transpose weights: WT[z][o][k] = W_z[k][o] ----------------
__global__ void k_transpose_w(const ushort* __restrict__ Wq, const ushort* __restrict__ Wk,
                              const ushort* __restrict__ Wv, ushort* __restrict__ WT) {
  __shared__ ushort tile[32][33];
  int z = blockIdx.z;
  const ushort* W = (z == 0) ? Wq : ((z == 1) ? Wk : Wv);
  ushort* dst = WT + z * 65536;
  int o0 = blockIdx.x * 32, k0 = blockIdx.y * 32;
  int tx = threadIdx.x, ty = threadIdx.y;
#pragma unroll
  for (int i = 0; i < 32; i += 8)
    tile[ty + i][tx] = W[(k0 + ty + i) * 256 + o0 + tx];
  __syncthreads();
#pragma unroll
  for (int i = 0; i < 32; i += 8)
    dst[(o0 + ty + i) * 256 + k0 + tx] = tile[tx][ty + i];
}

// -------- projections: Qh/Kh/Vh[head][n][d] = (X @ W + b) (Q pre-scaled 1/16) --------
__launch_bounds__(64)
__global__ void k_proj(const ushort* __restrict__ X, const ushort* __restrict__ WT,
                       const ushort* __restrict__ bq, const ushort* __restrict__ bk,
                       const ushort* __restrict__ bvp,
                       ushort* __restrict__ Qh, ushort* __restrict__ Kh, ushort* __restrict__ Vh) {
  int z = blockIdx.z;
  const ushort* WTz = WT + z * 65536;
  const ushort* bias = (z == 0) ? bq : ((z == 1) ? bk : bvp);
  ushort* out = (z == 0) ? Qh : ((z == 1) ? Kh : Vh);
  float scale = (z == 0) ? 0.0625f : 1.0f;  // fold scores/sqrt(256) into Q
  int n0 = blockIdx.x * 16;
  int head = blockIdx.y;
  int lane = threadIdx.x;
  int c = lane & 15, quad = lane >> 4;

  f32x4 acc[4];
#pragma unroll
  for (int i = 0; i < 4; ++i) acc[i] = (f32x4){0.f, 0.f, 0.f, 0.f};

  const ushort* xrow = X + (n0 + c) * 256;
#pragma unroll
  for (int kt = 0; kt < 8; ++kt) {
    bf16x8 a = *(const bf16x8*)(xrow + kt * 32 + quad * 8);
#pragma unroll
    for (int os = 0; os < 4; ++os) {
      bf16x8 b = *(const bf16x8*)(WTz + (head * 64 + os * 16 + c) * 256 + kt * 32 + quad * 8);
      acc[os] = __builtin_amdgcn_mfma_f32_16x16x32_bf16(a, b, acc[os], 0, 0, 0);
    }
  }
#pragma unroll
  for (int os = 0; os < 4; ++os) {
    float bval = bf2f(bias[head * 64 + os * 16 + c]);
#pragma unroll
    for (int r = 0; r < 4; ++r) {
      float val = (acc[os][r] + bval) * scale;
      out[head * (N_PTS * HD) + (n0 + quad * 4 + r) * HD + os * 16 + c] = f2bf(val);
    }
  }
}

// --------- smooth V over shifts {-4,-2,0,2,4} (circular in m) and transpose ----------
// VsT[g][d][m] = sum_s Vh[g][(m+s)%1600][d]
__global__ void k_smoothT(const ushort* __restrict__ Vh, ushort* __restrict__ VsT) {
  int idx = blockIdx.x * 256 + threadIdx.x;  // = (g*64+d)*1600 + m
  int m = idx % N_PTS;
  int t = idx / N_PTS;
  int d = t & 63, g = t >> 6;
  float s = 0.f;
#pragma unroll
  for (int sh = -4; sh <= 4; sh += 2) {
    int mm = m + sh; mm = (mm + N_PTS) % N_PTS;
    s += bf2f(Vh[g * (N_PTS * HD) + mm * HD + d]);
  }
  VsT[idx] = f2bf(s);
}

// ------- attention: one wave per (qtile, hq, kg); full keys; plain store per kg slice -------
__launch_bounds__(64)
__global__ void k_attn(const ushort* __restrict__ Qh, const ushort* __restrict__ Kh,
                       const ushort* __restrict__ VsT, float* __restrict__ Oacc4) {
  int qt = blockIdx.x;       // 0..99
  int hk = blockIdx.y;       // 0..15: hq*4 + kg
  int hq = hk >> 2, kg = hk & 3;
  int vg = (2 * hq - kg + 8) & 3;  // V head paired with this K head
  int lane = threadIdx.x, c = lane & 15, quad = lane >> 4;
  int n0 = qt * 16;

  __shared__ ushort P[16][40];  // 32 keys + pad (rows are 80 B -> 16B-aligned chunks)

  const ushort* qrow = Qh + (hq * N_PTS + n0 + c) * HD;
  bf16x8 qa0 = *(const bf16x8*)(qrow + quad * 8);
  bf16x8 qa1 = *(const bf16x8*)(qrow + 32 + quad * 8);

  f32x4 oacc[4];
#pragma unroll
  for (int i = 0; i < 4; ++i) oacc[i] = (f32x4){0.f, 0.f, 0.f, 0.f};
  float lsum[4] = {0.f, 0.f, 0.f, 0.f};

  for (int it = 0; it < 50; ++it) {
    int key0 = it * 32;
    const ushort* krow = Kh + (kg * N_PTS + key0 + c) * HD;
    bf16x8 kb00 = *(const bf16x8*)(krow + quad * 8);
    bf16x8 kb01 = *(const bf16x8*)(krow + 32 + quad * 8);
    bf16x8 kb10 = *(const bf16x8*)(krow + 16 * HD + quad * 8);
    bf16x8 kb11 = *(const bf16x8*)(krow + 16 * HD + 32 + quad * 8);

    f32x4 z = (f32x4){0.f, 0.f, 0.f, 0.f};
    f32x4 s0 = __builtin_amdgcn_mfma_f32_16x16x32_bf16(qa0, kb00, z, 0, 0, 0);
    s0 = __builtin_amdgcn_mfma_f32_16x16x32_bf16(qa1, kb01, s0, 0, 0, 0);
    f32x4 s1 = __builtin_amdgcn_mfma_f32_16x16x32_bf16(qa0, kb10, z, 0, 0, 0);
    s1 = __builtin_amdgcn_mfma_f32_16x16x32_bf16(qa1, kb11, s1, 0, 0, 0);

    // scores ~N(0, 0.5^2): softmax without max-subtraction is safe in f32
#pragma unroll
    for (int r = 0; r < 4; ++r) {
      float p0 = __expf(s0[r]);
      float p1 = __expf(s1[r]);
      lsum[r] += p0 + p1;
      P[quad * 4 + r][c] = f2bf(p0);        // C-layout -> [query row][key] in LDS
      P[quad * 4 + r][16 + c] = f2bf(p1);
    }
    __syncthreads();
    bf16x8 pa = *(const bf16x8*)(&P[c][quad * 8]);  // A-layout read back
#pragma unroll
    for (int ds = 0; ds < 4; ++ds) {
      const ushort* vrow = VsT + (vg * HD + ds * 16 + c) * N_PTS + key0;
      bf16x8 vb = *(const bf16x8*)(vrow + quad * 8);
      oacc[ds] = __builtin_amdgcn_mfma_f32_16x16x32_bf16(pa, vb, oacc[ds], 0, 0, 0);
    }
    __syncthreads();
  }

  // reduce l over the 16 lanes of each quad (c-lanes share the same query rows)
#pragma unroll
  for (int r = 0; r < 4; ++r) {
    float l = lsum[r];
#pragma unroll
    for (int m = 1; m < 16; m <<= 1) l += __shfl_xor(l, m, 64);
    lsum[r] = l;
  }

  // normalize + weight locally (this wave owns the full denominator); one store per element
  float w = (kg == ((hq + 2) & 3)) ? 2.0f : 1.0f;
  float* dst = Oacc4 + (size_t)kg * (N_PTS * 256);
#pragma unroll
  for (int ds = 0; ds < 4; ++ds)
#pragma unroll
    for (int r = 0; r < 4; ++r)
      dst[(n0 + quad * 4 + r) * 256 + hq * 64 + ds * 16 + c] = w * oacc[ds][r] / lsum[r];
}

// ---------------- sum the 4 kg slices, emit in detected output dtype ----------------
__global__ void k_out(const float* __restrict__ Oacc4, const int* __restrict__ flag,
                      void* __restrict__ out) {
  int idx = blockIdx.x * 256 + threadIdx.x;
  float s = Oacc4[idx] + Oacc4[409600 + idx] + Oacc4[819200 + idx] + Oacc4[1228800 + idx];
  if (*flag) ((float*)out)[idx] = s;
  else       ((ushort*)out)[idx] = f2bf(s);
}

extern "C" void kernel_launch(void* const* d_in, const int* in_sizes, int n_in,
                              void* d_out, int out_size, void* d_ws, size_t ws_size,
                              hipStream_t stream) {
  char* ws = (char*)d_ws;
  ushort* Xc   = (ushort*)(ws + OFF_XC);
  ushort* Wqc  = (ushort*)(ws + OFF_WQC);
  ushort* bqc  = (ushort*)(ws + OFF_BQC);
  ushort* Wkc  = (ushort*)(ws + OFF_WKC);
  ushort* bkc  = (ushort*)(ws + OFF_BKC);
  ushort* Wvc  = (ushort*)(ws + OFF_WVC);
  ushort* bvc  = (ushort*)(ws + OFF_BVC);
  ushort* WT   = (ushort*)(ws + OFF_WT);
  float*  Oacc4= (float*)(ws + OFF_OACC4);
  ushort* Qh   = (ushort*)(ws + OFF_QH);
  ushort* Kh   = (ushort*)(ws + OFF_KH);
  ushort* Vh   = (ushort*)(ws + OFF_VH);
  ushort* VsT  = (ushort*)(ws + OFF_VST);
  int*    flag = (int*)(ws + OFF_FLAG);

  k_detect<<<1, 256, 0, stream>>>((const ushort*)d_in[0], flag);
  k_convert<<<dim3(1600, 7), 256, 0, stream>>>(d_in[0], d_in[1], d_in[2], d_in[3],
                                               d_in[4], d_in[5], d_in[6], ws, flag);
  k_transpose_w<<<dim3(8, 8, 3), dim3(32, 8), 0, stream>>>(Wqc, Wkc, Wvc, WT);
  k_proj<<<dim3(100, 4, 3), 64, 0, stream>>>(Xc, WT, bqc, bkc, bvc, Qh, Kh, Vh);
  k_smoothT<<<1600, 256, 0, stream>>>(Vh, VsT);
  k_attn<<<dim3(100, 16), 64, 0, stream>>>(Qh, Kh, VsT, Oacc4);
  k_out<<<1600, 256, 0, stream>>>(Oacc4, flag, d_out);
}

// Round 4
// 141.143 us; speedup vs baseline: 1.2488x; 1.2488x over previous
//
#include <hip/hip_runtime.h>
#include <stdint.h>

typedef __attribute__((ext_vector_type(8))) __bf16 bf16x8;
typedef __attribute__((ext_vector_type(4))) float f32x4;

#define N_PTS 1600
#define HD    64

// ---- workspace layout (bytes). Canonical inputs + WT live in [0, 1607168);
// ---- they are dead after k_proj, and Oacc4 (written only in k_attn) overlaps them.
#define OFF_XC    0u
#define OFF_WQC   819200u
#define OFF_BQC   950272u
#define OFF_WKC   950784u
#define OFF_BKC   1081856u
#define OFF_WVC   1082368u
#define OFF_BVC   1213440u
#define OFF_WT    1213952u    //  393216 -> ends 1607168
#define OFF_OACC4 0u          // 6553600 : [4 kg][1600][256] f32 (overlaps the above)
#define OFF_QH    6553600u    //  819200 : [4][1600][64] bf16, pre-scaled 1/16
#define OFF_KH    7372800u    //  819200 : [4][1600][64]
#define OFF_VST   8192000u    //  819200 : [4][64][1600] smoothed V^T
#define OFF_VHT   9011200u    //  819200 : [4][64][1600] raw V^T (dead after k_smooth)
#define OFF_FLAG  9830400u

__device__ __forceinline__ float bf2f(ushort h) {
  union { uint32_t u; float f; } v; v.u = ((uint32_t)h) << 16; return v.f;
}
__device__ __forceinline__ ushort f2bf(float f) {
  union { float f; uint32_t u; } v; v.f = f;
  uint32_t u = v.u;
  return (ushort)((u + 0x7FFFu + ((u >> 16) & 1u)) >> 16);
}

// ---- dtype detector: even-indexed ushorts of an f32 buffer are mantissa garbage ----
__global__ void k_detect(const ushort* __restrict__ x, int* __restrict__ flag) {
  __shared__ int bad;
  if (threadIdx.x == 0) bad = 0;
  __syncthreads();
  int t = threadIdx.x;
  int local = 0;
#pragma unroll
  for (int i = 0; i < 16; ++i) {
    float v = bf2f(x[(t * 16 + i) * 2]);
    if (!(fabsf(v) < 1e4f)) local = 1;
  }
  if (local) atomicOr(&bad, 1);
  __syncthreads();
  if (t == 0) *flag = bad;
}

// ---- canonicalize all 7 inputs to bf16 in ws (flat-indexed, single grid) ----
__global__ void k_convert(const void* __restrict__ s0, const void* __restrict__ s1,
                          const void* __restrict__ s2, const void* __restrict__ s3,
                          const void* __restrict__ s4, const void* __restrict__ s5,
                          const void* __restrict__ s6, char* __restrict__ ws,
                          const int* __restrict__ flag) {
  int i = blockIdx.x * 256 + threadIdx.x;
  const void* src; unsigned off; int local;
  if      (i < 409600) { src = s0; off = OFF_XC;  local = i; }
  else if (i < 475136) { src = s1; off = OFF_WQC; local = i - 409600; }
  else if (i < 475392) { src = s2; off = OFF_BQC; local = i - 475136; }
  else if (i < 540928) { src = s3; off = OFF_WKC; local = i - 475392; }
  else if (i < 541184) { src = s4; off = OFF_BKC; local = i - 540928; }
  else if (i < 606720) { src = s5; off = OFF_WVC; local = i - 541184; }
  else if (i < 606976) { src = s6; off = OFF_BVC; local = i - 606720; }
  else return;
  ushort* dst = (ushort*)(ws + off);
  if (*flag) dst[local] = f2bf(((const float*)src)[local]);
  else       dst[local] = ((const ushort*)src)[local];
}

// ---------------- transpose weights: WT[z][o][k] = W_z[k][o] ----------------
__global__ void k_transpose_w(const ushort* __restrict__ Wq, const ushort* __restrict__ Wk,
                              const ushort* __restrict__ Wv, ushort* __restrict__ WT) {
  __shared__ ushort tile[32][33];
  int z = blockIdx.z;
  const ushort* W = (z == 0) ? Wq : ((z == 1) ? Wk : Wv);
  ushort* dst = WT + z * 65536;
  int o0 = blockIdx.x * 32, k0 = blockIdx.y * 32;
  int tx = threadIdx.x, ty = threadIdx.y;
#pragma unroll
  for (int i = 0; i < 32; i += 8)
    tile[ty + i][tx] = W[(k0 + ty + i) * 256 + o0 + tx];
  __syncthreads();
#pragma unroll
  for (int i = 0; i < 32; i += 8)
    dst[(o0 + ty + i) * 256 + k0 + tx] = tile[tx][ty + i];
}

// -------- projections. 4 waves/block = 4 heads sharing X rows via L1.
// Q pre-scaled 1/16; V written TRANSPOSED: VhT[head][d][n] --------
__launch_bounds__(256)
__global__ void k_proj(const ushort* __restrict__ X, const ushort* __restrict__ WT,
                       const ushort* __restrict__ bq, const ushort* __restrict__ bk,
                       const ushort* __restrict__ bvp,
                       ushort* __restrict__ Qh, ushort* __restrict__ Kh, ushort* __restrict__ VhT) {
  int z = blockIdx.z;
  const ushort* WTz = WT + z * 65536;
  const ushort* bias = (z == 0) ? bq : ((z == 1) ? bk : bvp);
  float scale = (z == 0) ? 0.0625f : 1.0f;
  int n0 = blockIdx.x * 16;
  int head = threadIdx.x >> 6;
  int lane = threadIdx.x & 63;
  int c = lane & 15, quad = lane >> 4;

  f32x4 acc[4];
#pragma unroll
  for (int i = 0; i < 4; ++i) acc[i] = (f32x4){0.f, 0.f, 0.f, 0.f};

  const ushort* xrow = X + (n0 + c) * 256;
#pragma unroll
  for (int kt = 0; kt < 8; ++kt) {
    bf16x8 a = *(const bf16x8*)(xrow + kt * 32 + quad * 8);
#pragma unroll
    for (int os = 0; os < 4; ++os) {
      bf16x8 b = *(const bf16x8*)(WTz + (head * 64 + os * 16 + c) * 256 + kt * 32 + quad * 8);
      acc[os] = __builtin_amdgcn_mfma_f32_16x16x32_bf16(a, b, acc[os], 0, 0, 0);
    }
  }
  if (z == 2) {
#pragma unroll
    for (int os = 0; os < 4; ++os) {
      float bval = bf2f(bias[head * 64 + os * 16 + c]);
      ushort4 v;
      v.x = f2bf(acc[os][0] + bval); v.y = f2bf(acc[os][1] + bval);
      v.z = f2bf(acc[os][2] + bval); v.w = f2bf(acc[os][3] + bval);
      *(ushort4*)(VhT + (head * 64 + os * 16 + c) * N_PTS + n0 + quad * 4) = v;
    }
  } else {
    ushort* out = (z == 0) ? Qh : Kh;
#pragma unroll
    for (int os = 0; os < 4; ++os) {
      float bval = bf2f(bias[head * 64 + os * 16 + c]);
#pragma unroll
      for (int r = 0; r < 4; ++r)
        out[head * (N_PTS * HD) + (n0 + quad * 4 + r) * HD + os * 16 + c] =
            f2bf((acc[os][r] + bval) * scale);
    }
  }
}

// --- smooth along m (coalesced now): VsT[g][d][m] = sum_{sh in +-{0,2,4}} VhT[g][d][(m+sh)%1600]
__global__ void k_smooth(const ushort* __restrict__ VhT, ushort* __restrict__ VsT) {
  int idx = blockIdx.x * 256 + threadIdx.x;  // (g*64+d)*1600 + m
  int m = idx % N_PTS;
  int base = idx - m;
  float s = 0.f;
#pragma unroll
  for (int sh = -4; sh <= 4; sh += 2)
    s += bf2f(VhT[base + ((m + sh + N_PTS) % N_PTS)]);
  VsT[idx] = f2bf(s);
}

// ---- build PV B-fragment from S^T C-layout via quad shuffles (no LDS, no barrier) ----
__device__ __forceinline__ bf16x8 build_pfrag(const f32x4& s0, const f32x4& s1,
                                              int sA, int sB, bool low, float& lpart) {
  uint32_t pk[4];
#pragma unroll
  for (int r = 0; r < 4; ++r) {
    float p0 = __expf(s0[r]);
    float p1 = __expf(s1[r]);
    lpart += p0 + p1;
    pk[r] = (uint32_t)f2bf(p0) | ((uint32_t)f2bf(p1) << 16);
  }
  union { ushort us[8]; bf16x8 v; } pb;
#pragma unroll
  for (int j = 0; j < 4; ++j) {
    uint32_t u = (uint32_t)__shfl((int)pk[j], sA, 64);
    pb.us[j] = low ? (ushort)u : (ushort)(u >> 16);
  }
#pragma unroll
  for (int j = 0; j < 4; ++j) {
    uint32_t u = (uint32_t)__shfl((int)pk[j], sB, 64);
    pb.us[4 + j] = low ? (ushort)u : (ushort)(u >> 16);
  }
  return pb.v;
}

// ---- attention: block = (qtile, hp*4+kg), 4 waves = 4 key-splits.
// Each wave serves heads {hp, hp+2} (same kg AND same vg -> K/V loads shared). ----
__launch_bounds__(256, 4)
__global__ void k_attn(const ushort* __restrict__ Qh, const ushort* __restrict__ Kh,
                       const ushort* __restrict__ VsT, float* __restrict__ Oacc4) {
  int qt = blockIdx.x;
  int yy = blockIdx.y;           // 0..7 : hp*4 + kg
  int hp = yy >> 2, kg = yy & 3;
  int vg = (2 * hp - kg + 8) & 3;
  int tid = threadIdx.x, sp = tid >> 6, lane = tid & 63;
  int c = lane & 15, quad = lane >> 4;
  int n0 = qt * 16;

  __shared__ float ObufT[2][4][16][68];  // [head][sp][q][d] padded
  __shared__ float Lbuf[2][4][16];

  const ushort* q0row = Qh + ((hp    ) * N_PTS + n0 + c) * HD;
  const ushort* q1row = Qh + ((hp + 2) * N_PTS + n0 + c) * HD;
  bf16x8 qa00 = *(const bf16x8*)(q0row + quad * 8);
  bf16x8 qa01 = *(const bf16x8*)(q0row + 32 + quad * 8);
  bf16x8 qa10 = *(const bf16x8*)(q1row + quad * 8);
  bf16x8 qa11 = *(const bf16x8*)(q1row + 32 + quad * 8);

  f32x4 oacc0[4], oacc1[4];
#pragma unroll
  for (int i = 0; i < 4; ++i) {
    oacc0[i] = (f32x4){0.f, 0.f, 0.f, 0.f};
    oacc1[i] = (f32x4){0.f, 0.f, 0.f, 0.f};
  }
  float lp0 = 0.f, lp1 = 0.f;

  int kbase = (sp < 2) ? sp * 416 : 832 + (sp - 2) * 384;  // 13/13/12/12 tiles of 32
  int iters = (sp < 2) ? 13 : 12;
  int sA = c + 16 * ((quad & 1) * 2);
  int sB = sA + 16;
  bool low = (quad < 2);
  const f32x4 z4 = (f32x4){0.f, 0.f, 0.f, 0.f};

  for (int it = 0; it < iters; ++it) {
    int key0 = kbase + it * 32;
    const ushort* krow = Kh + (kg * N_PTS + key0 + c) * HD;
    bf16x8 kb00 = *(const bf16x8*)(krow + quad * 8);
    bf16x8 kb01 = *(const bf16x8*)(krow + 32 + quad * 8);
    bf16x8 kb10 = *(const bf16x8*)(krow + 16 * HD + quad * 8);
    bf16x8 kb11 = *(const bf16x8*)(krow + 16 * HD + 32 + quad * 8);
    bf16x8 vb[4];
#pragma unroll
    for (int ds = 0; ds < 4; ++ds)
      vb[ds] = *(const bf16x8*)(VsT + (vg * HD + ds * 16 + c) * N_PTS + key0 + quad * 8);

    // head 0: S^T = mfma(K, Q) -> lane (c,quad) reg r = score(q=n0+c, key=key0+{0,16}+quad*4+r)
    f32x4 s0 = __builtin_amdgcn_mfma_f32_16x16x32_bf16(kb00, qa00, z4, 0, 0, 0);
    s0 = __builtin_amdgcn_mfma_f32_16x16x32_bf16(kb01, qa01, s0, 0, 0, 0);
    f32x4 s1 = __builtin_amdgcn_mfma_f32_16x16x32_bf16(kb10, qa00, z4, 0, 0, 0);
    s1 = __builtin_amdgcn_mfma_f32_16x16x32_bf16(kb11, qa01, s1, 0, 0, 0);
    bf16x8 pb = build_pfrag(s0, s1, sA, sB, low, lp0);
#pragma unroll
    for (int ds = 0; ds < 4; ++ds)
      oacc0[ds] = __builtin_amdgcn_mfma_f32_16x16x32_bf16(vb[ds], pb, oacc0[ds], 0, 0, 0);

    // head 1 (hp+2): same K and V fragments
    s0 = __builtin_amdgcn_mfma_f32_16x16x32_bf16(kb00, qa10, z4, 0, 0, 0);
    s0 = __builtin_amdgcn_mfma_f32_16x16x32_bf16(kb01, qa11, s0, 0, 0, 0);
    s1 = __builtin_amdgcn_mfma_f32_16x16x32_bf16(kb10, qa10, z4, 0, 0, 0);
    s1 = __builtin_amdgcn_mfma_f32_16x16x32_bf16(kb11, qa11, s1, 0, 0, 0);
    bf16x8 pb1 = build_pfrag(s0, s1, sA, sB, low, lp1);
#pragma unroll
    for (int ds = 0; ds < 4; ++ds)
      oacc1[ds] = __builtin_amdgcn_mfma_f32_16x16x32_bf16(vb[ds], pb1, oacc1[ds], 0, 0, 0);
  }

  // denominator: sum the 4 quads (lanes c, c+16, c+32, c+48 all hold q=c partials)
  lp0 += __shfl_xor(lp0, 16, 64); lp0 += __shfl_xor(lp0, 32, 64);
  lp1 += __shfl_xor(lp1, 16, 64); lp1 += __shfl_xor(lp1, 32, 64);

  // oaccX[ds] reg r = O^T[d = ds*16+quad*4+r][q=c] partial over this wave's keys
#pragma unroll
  for (int ds = 0; ds < 4; ++ds) {
    *(f32x4*)&ObufT[0][sp][c][ds * 16 + quad * 4] = oacc0[ds];
    *(f32x4*)&ObufT[1][sp][c][ds * 16 + quad * 4] = oacc1[ds];
  }
  if (quad == 0) { Lbuf[0][sp][c] = lp0; Lbuf[1][sp][c] = lp1; }
  __syncthreads();

  int q = tid >> 4, d0 = (tid & 15) * 4;
#pragma unroll
  for (int h = 0; h < 2; ++h) {
    f32x4 a = *(f32x4*)&ObufT[h][0][q][d0];
    a += *(f32x4*)&ObufT[h][1][q][d0];
    a += *(f32x4*)&ObufT[h][2][q][d0];
    a += *(f32x4*)&ObufT[h][3][q][d0];
    float l = Lbuf[h][0][q] + Lbuf[h][1][q] + Lbuf[h][2][q] + Lbuf[h][3][q];
    int hq = hp + 2 * h;
    float w = (h == 0) ? ((kg == ((hp + 2) & 3)) ? 2.f : 1.f)
                       : ((kg == hp) ? 2.f : 1.f);
    float inv = w / l;
    f32x4 o = a * inv;
    *(f32x4*)&Oacc4[(size_t)kg * 409600 + (size_t)(n0 + q) * 256 + hq * 64 + d0] = o;
  }
}

// ---------------- sum the 4 kg slices, emit in detected output dtype ----------------
__global__ void k_out(const float* __restrict__ Oacc4, const int* __restrict__ flag,
                      void* __restrict__ out) {
  int idx = blockIdx.x * 256 + threadIdx.x;
  float s = Oacc4[idx] + Oacc4[409600 + idx] + Oacc4[819200 + idx] + Oacc4[1228800 + idx];
  if (*flag) ((float*)out)[idx] = s;
  else       ((ushort*)out)[idx] = f2bf(s);
}

extern "C" void kernel_launch(void* const* d_in, const int* in_sizes, int n_in,
                              void* d_out, int out_size, void* d_ws, size_t ws_size,
                              hipStream_t stream) {
  char* ws = (char*)d_ws;
  ushort* Wqc  = (ushort*)(ws + OFF_WQC);
  ushort* bqc  = (ushort*)(ws + OFF_BQC);
  ushort* Wkc  = (ushort*)(ws + OFF_WKC);
  ushort* bkc  = (ushort*)(ws + OFF_BKC);
  ushort* Wvc  = (ushort*)(ws + OFF_WVC);
  ushort* bvc  = (ushort*)(ws + OFF_BVC);
  ushort* Xc   = (ushort*)(ws + OFF_XC);
  ushort* WT   = (ushort*)(ws + OFF_WT);
  float*  Oacc4= (float*)(ws + OFF_OACC4);
  ushort* Qh   = (ushort*)(ws + OFF_QH);
  ushort* Kh   = (ushort*)(ws + OFF_KH);
  ushort* VsT  = (ushort*)(ws + OFF_VST);
  ushort* VhT  = (ushort*)(ws + OFF_VHT);
  int*    flag = (int*)(ws + OFF_FLAG);

  k_detect<<<1, 256, 0, stream>>>((const ushort*)d_in[0], flag);
  k_convert<<<2372, 256, 0, stream>>>(d_in[0], d_in[1], d_in[2], d_in[3],
                                      d_in[4], d_in[5], d_in[6], ws, flag);
  k_transpose_w<<<dim3(8, 8, 3), dim3(32, 8), 0, stream>>>(Wqc, Wkc, Wvc, WT);
  k_proj<<<dim3(100, 1, 3), 256, 0, stream>>>(Xc, WT, bqc, bkc, bvc, Qh, Kh, VhT);
  k_smooth<<<1600, 256, 0, stream>>>(VhT, VsT);
  k_attn<<<dim3(100, 8), 256, 0, stream>>>(Qh, Kh, VsT, Oacc4);
  k_out<<<1600, 256, 0, stream>>>(Oacc4, flag, d_out);
}